// Round 3
// baseline (511.149 us; speedup 1.0000x reference)
//
#include <hip/hip_runtime.h>
#include <stdint.h>

typedef unsigned short u16t;
typedef unsigned int   u32t;
typedef __attribute__((ext_vector_type(8))) short frag8;   // 8 bf16 = 4 VGPRs
typedef __attribute__((ext_vector_type(4))) float fragc;   // 4 fp32 acc

#define NN 50000
#define NE 800000
#define NB_EDGE 12500          // edge blocks (64 edges each; NE = 64*12500 exactly)
#define NB_NODE 782            // node-MLP blocks (64 nodes each)

// packed-weight offsets in u16 elements within d_ws (weights: 139264 B)
#define W1P 0
#define W2P 24576
#define W3P 40960
#define U1P 49152
#define U2P 61440
// bf16 mirrors of nf/st in d_ws (byte offsets; both 16B-aligned)
#define NFB_OFF 139264                     // u16 nfb[NN*64]  (6.4 MB)
#define STB_OFF (NFB_OFF + 6400000)        // u16 stb[NN*32]  (3.2 MB)

// prep grid partition
#define PB_PACK 34
#define PB_ZERO 3125           // zero out1: NN*16 float4
#define PB_NF   1563           // cvt nf: NN*64 = 3.2M elems, 2048/block
#define PB_ST   782            // cvt st: NN*32 = 1.6M elems

__device__ __forceinline__ u16t f2bf(float f) {
    u32t x = __builtin_bit_cast(u32t, f);
    x = x + 0x7FFFu + ((x >> 16) & 1u);   // RNE
    return (u16t)(x >> 16);
}

__device__ __forceinline__ u32t pack_bf2(float x, float y) {
#if __has_builtin(__builtin_amdgcn_cvt_pk_bf16_f32)
    typedef __attribute__((ext_vector_type(2))) __bf16 bfv2;
    bfv2 r = __builtin_amdgcn_cvt_pk_bf16_f32(x, y);
    return __builtin_bit_cast(u32t, r);
#else
    return (u32t)f2bf(x) | ((u32t)f2bf(y) << 16);
#endif
}

// ---------------------------------------------------------------------------
// Weight prepack core: W (K x N row-major fp32) -> bf16 B-frag order.
// ---------------------------------------------------------------------------
__device__ __forceinline__ void prepack_one(int t, const float* w1, const float* w2,
                                            const float* w3, const float* u1,
                                            const float* u2, u16t* out) {
    const float* src; u16t* dst; int id, K, N;
    if (t < 3072)      { id = t;        K = 192; N = 128; src = w1; dst = out + W1P; }
    else if (t < 5120) { id = t - 3072; K = 128; N = 128; src = w2; dst = out + W2P; }
    else if (t < 6144) { id = t - 5120; K = 128; N = 64;  src = w3; dst = out + W3P; }
    else if (t < 7680) { id = t - 6144; K = 96;  N = 128; src = u1; dst = out + U1P; }
    else if (t < 8704) { id = t - 7680; K = 128; N = 64;  src = u2; dst = out + U2P; }
    else return;
    int lane = id & 63;
    int fl   = id >> 6;
    int ksteps = K >> 5;
    int nb = fl / ksteps, ks = fl - nb * ksteps;
    int n  = nb * 16 + (lane & 15);
    int k0 = ks * 32 + (lane >> 4) * 8;
    const float* s = src + (size_t)k0 * N + n;
    uint4 v;
    v.x = pack_bf2(s[0],           s[(size_t)N]);
    v.y = pack_bf2(s[2*(size_t)N], s[3*(size_t)N]);
    v.z = pack_bf2(s[4*(size_t)N], s[5*(size_t)N]);
    v.w = pack_bf2(s[6*(size_t)N], s[7*(size_t)N]);
    *(uint4*)(dst + (size_t)id * 8) = v;
}

// fused prep: prepack weights | zero out1 | cvt nf->bf16 | cvt st->bf16
__global__ void prep_k(const float* __restrict__ w1, const float* __restrict__ w2,
                       const float* __restrict__ w3, const float* __restrict__ u1,
                       const float* __restrict__ u2, u16t* __restrict__ wp,
                       float4* __restrict__ out1v,
                       const float* __restrict__ nf, u16t* __restrict__ nfb,
                       const float* __restrict__ st, u16t* __restrict__ stb) {
    int b = blockIdx.x;
    if (b < PB_PACK) {
        prepack_one(b * 256 + threadIdx.x, w1, w2, w3, u1, u2, wp);
    } else if (b < PB_PACK + PB_ZERO) {
        int i = (b - PB_PACK) * 256 + threadIdx.x;
        if (i < NN * 16) out1v[i] = make_float4(0.f, 0.f, 0.f, 0.f);
    } else if (b < PB_PACK + PB_ZERO + PB_NF) {
        int i = ((b - PB_PACK - PB_ZERO) * 256 + threadIdx.x) * 8;
        if (i < NN * 64) {
            float4 a = *(const float4*)(nf + i);
            float4 c = *(const float4*)(nf + i + 4);
            uint4 v;
            v.x = pack_bf2(a.x, a.y); v.y = pack_bf2(a.z, a.w);
            v.z = pack_bf2(c.x, c.y); v.w = pack_bf2(c.z, c.w);
            *(uint4*)(nfb + i) = v;
        }
    } else {
        int i = ((b - PB_PACK - PB_ZERO - PB_NF) * 256 + threadIdx.x) * 8;
        if (i < NN * 32) {
            float4 a = *(const float4*)(st + i);
            float4 c = *(const float4*)(st + i + 4);
            uint4 v;
            v.x = pack_bf2(a.x, a.y); v.y = pack_bf2(a.z, a.w);
            v.z = pack_bf2(c.x, c.y); v.w = pack_bf2(c.z, c.w);
            *(uint4*)(stb + i) = v;
        }
    }
}

// ---------------------------------------------------------------------------
// Fused main kernel, direct-gather edition.
// A-fragments for layer 1 (X = [nf[s]|nf[d]|ef|st[s]]) are gathered straight
// from global per lane (16B each) -> NO X staging, NO X LDS region.
// Only H (64x128 bf16, XOR-swizzled) lives in LDS. 3 barriers (edge), 0 (node).
// LDS 16.6 KB; __launch_bounds__(256,6): VGPR cap 85, no spills.
// ---------------------------------------------------------------------------
__global__ __launch_bounds__(256, 6)
void fused_k(const u16t* __restrict__ nfb, const u16t* __restrict__ stb,
             const float* __restrict__ nf, const float* __restrict__ ef,
             const float* __restrict__ b1, const float* __restrict__ b2,
             const float* __restrict__ b3, const float* __restrict__ ub1,
             const float* __restrict__ ub2, const int* __restrict__ eidx,
             const u16t* __restrict__ wp,
             float* __restrict__ out0, float* __restrict__ out1) {
    __shared__ __align__(16) u16t H[64 * 128];   // 16384 B, chunk-XOR swizzled
    __shared__ int dstL[64];
    const int tid  = threadIdx.x;
    const int lane = tid & 63;
    const int wv   = tid >> 6;
    const int lr   = lane & 15;
    const int qd   = lane >> 4;
    const int sw   = lr & 7;

    if (blockIdx.x >= NB_EDGE) {
        // ---------------- node role (barrier-free) ----------------
        const int n0  = (blockIdx.x - NB_EDGE) * 64;
        const int m16 = wv * 16;
        int nd  = n0 + m16 + lr;
        int ncl = nd < NN ? nd : NN - 1;          // clamp for loads

        fragc acc[8];
        #pragma unroll
        for (int n = 0; n < 8; n++) acc[n] = (fragc){0.f, 0.f, 0.f, 0.f};
        {
            const frag8* w = (const frag8*)(wp + U1P);
            #pragma unroll
            for (int ks = 0; ks < 3; ks++) {
                frag8 a;
                if (ks < 2) a = *(const frag8*)(nfb + (size_t)ncl * 64 + ks * 32 + qd * 8);
                else        a = *(const frag8*)(stb + (size_t)ncl * 32 + qd * 8);
                #pragma unroll
                for (int n = 0; n < 8; n++)
                    acc[n] = __builtin_amdgcn_mfma_f32_16x16x32_bf16(
                        a, w[(n * 3 + ks) * 64 + lane], acc[n], 0, 0, 0);
            }
        }
        // write own H rows (wave-private 16 rows; no barrier needed)
        #pragma unroll
        for (int n = 0; n < 8; n++) {
            float bs = ub1[n * 16 + lr];
            int cb = 2 * n + (lr >> 3);
            #pragma unroll
            for (int r = 0; r < 4; r++) {
                int row = m16 + qd * 4 + r;
                float v = acc[n][r] + bs;
                H[row * 128 + ((cb ^ (row & 7)) << 3) + (lr & 7)] = f2bf(v > 0.f ? v : 0.f);
            }
        }
        fragc a2[4];
        #pragma unroll
        for (int n = 0; n < 4; n++) a2[n] = (fragc){0.f, 0.f, 0.f, 0.f};
        {
            const frag8* w = (const frag8*)(wp + U2P);
            #pragma unroll
            for (int ks = 0; ks < 4; ks++) {
                int c = ks * 4 + qd;
                frag8 a = *(const frag8*)(H + (m16 + lr) * 128 + ((c ^ sw) << 3));
                #pragma unroll
                for (int n = 0; n < 4; n++)
                    a2[n] = __builtin_amdgcn_mfma_f32_16x16x32_bf16(
                        a, w[(n * 4 + ks) * 64 + lane], a2[n], 0, 0, 0);
            }
        }
        #pragma unroll
        for (int n = 0; n < 4; n++) {
            float bs = ub2[n * 16 + lr];
            #pragma unroll
            for (int r = 0; r < 4; r++) {
                int nd2 = n0 + m16 + qd * 4 + r;
                if (nd2 < NN) {
                    int col = n * 16 + lr;
                    out0[(size_t)nd2 * 64 + col] = nf[(size_t)nd2 * 64 + col] + a2[n][r] + bs;
                }
            }
        }
        return;
    }

    // ---------------- edge role ----------------
    const int e0  = blockIdx.x * 64;
    const int nb0 = 2 * wv, nb1 = 2 * wv + 1;

    // per-lane src/dst for the 4 m-tiles (row = m*16 + lr)
    int sN[4], dN[4];
    #pragma unroll
    for (int m = 0; m < 4; m++) {
        int e = e0 + m * 16 + lr;
        sN[m] = eidx[2 * e];
        dN[m] = eidx[2 * e + 1];
    }
    if (tid < 64) dstL[tid] = eidx[2 * (e0 + tid) + 1];

    // ---- layer 1: X(64x192) @ W1(192x128); A-frags gathered from global.
    // X cols: [0,64)=nfb[s], [64,128)=nfb[d], [128,160)=ef(fp32->bf16), [160,192)=stb[s]
    fragc acc[2][4];
    #pragma unroll
    for (int i = 0; i < 2; i++)
        #pragma unroll
        for (int m = 0; m < 4; m++) acc[i][m] = (fragc){0.f, 0.f, 0.f, 0.f};
    {
        const frag8* w = (const frag8*)(wp + W1P);
        #pragma unroll
        for (int ks = 0; ks < 6; ks++) {
            frag8 w0 = w[(nb0 * 6 + ks) * 64 + lane];
            frag8 w1 = w[(nb1 * 6 + ks) * 64 + lane];
            #pragma unroll
            for (int m = 0; m < 4; m++) {
                frag8 a;
                if (ks < 2) {
                    a = *(const frag8*)(nfb + (size_t)sN[m] * 64 + ks * 32 + qd * 8);
                } else if (ks < 4) {
                    a = *(const frag8*)(nfb + (size_t)dN[m] * 64 + (ks - 2) * 32 + qd * 8);
                } else if (ks == 4) {
                    const float4* ep = (const float4*)(ef + (size_t)(e0 + m * 16 + lr) * 32 + qd * 8);
                    float4 v0 = ep[0], v1 = ep[1];
                    uint4 u;
                    u.x = pack_bf2(v0.x, v0.y); u.y = pack_bf2(v0.z, v0.w);
                    u.z = pack_bf2(v1.x, v1.y); u.w = pack_bf2(v1.z, v1.w);
                    a = __builtin_bit_cast(frag8, u);
                } else {
                    a = *(const frag8*)(stb + (size_t)sN[m] * 32 + qd * 8);
                }
                acc[0][m] = __builtin_amdgcn_mfma_f32_16x16x32_bf16(a, w0, acc[0][m], 0, 0, 0);
                acc[1][m] = __builtin_amdgcn_mfma_f32_16x16x32_bf16(a, w1, acc[1][m], 0, 0, 0);
            }
        }
    }
    // write H (swizzled); region fresh, no prior readers
    #pragma unroll
    for (int i = 0; i < 2; i++) {
        int nb = nb0 + i;
        float bs = b1[nb * 16 + lr];
        int cb = 2 * nb + (lr >> 3);
        #pragma unroll
        for (int m = 0; m < 4; m++)
            #pragma unroll
            for (int r = 0; r < 4; r++) {
                int row = m * 16 + qd * 4 + r;
                float v = acc[i][m][r] + bs;
                H[row * 128 + ((cb ^ (row & 7)) << 3) + (lr & 7)] = f2bf(v > 0.f ? v : 0.f);
            }
    }
    __syncthreads();             // B1: H complete (also covers dstL)

    // ---- layer 2: H(64x128) @ W2(128x128)
    #pragma unroll
    for (int i = 0; i < 2; i++)
        #pragma unroll
        for (int m = 0; m < 4; m++) acc[i][m] = (fragc){0.f, 0.f, 0.f, 0.f};
    {
        const frag8* w = (const frag8*)(wp + W2P);
        #pragma unroll
        for (int ks = 0; ks < 4; ks++) {
            frag8 w0 = w[(nb0 * 4 + ks) * 64 + lane];
            frag8 w1 = w[(nb1 * 4 + ks) * 64 + lane];
            int c = ks * 4 + qd;
            #pragma unroll
            for (int m = 0; m < 4; m++) {
                frag8 a = *(const frag8*)(H + (m * 16 + lr) * 128 + ((c ^ sw) << 3));
                acc[0][m] = __builtin_amdgcn_mfma_f32_16x16x32_bf16(a, w0, acc[0][m], 0, 0, 0);
                acc[1][m] = __builtin_amdgcn_mfma_f32_16x16x32_bf16(a, w1, acc[1][m], 0, 0, 0);
            }
        }
    }
    __syncthreads();             // B2: all H reads done, region reusable
    #pragma unroll
    for (int i = 0; i < 2; i++) {
        int nb = nb0 + i;
        float bs = b2[nb * 16 + lr];
        int cb = 2 * nb + (lr >> 3);
        #pragma unroll
        for (int m = 0; m < 4; m++)
            #pragma unroll
            for (int r = 0; r < 4; r++) {
                int row = m * 16 + qd * 4 + r;
                float v = acc[i][m][r] + bs;
                H[row * 128 + ((cb ^ (row & 7)) << 3) + (lr & 7)] = f2bf(v > 0.f ? v : 0.f);
            }
    }
    __syncthreads();             // B3: H' complete

    // ---- layer 3: H'(64x128) @ W3(128x64); wave owns N-block wv (16 cols)
    fragc a3[4];
    #pragma unroll
    for (int m = 0; m < 4; m++) a3[m] = (fragc){0.f, 0.f, 0.f, 0.f};
    {
        const frag8* w = (const frag8*)(wp + W3P);
        #pragma unroll
        for (int ks = 0; ks < 4; ks++) {
            frag8 wf = w[(wv * 4 + ks) * 64 + lane];
            int c = ks * 4 + qd;
            #pragma unroll
            for (int m = 0; m < 4; m++) {
                frag8 a = *(const frag8*)(H + (m * 16 + lr) * 128 + ((c ^ sw) << 3));
                a3[m] = __builtin_amdgcn_mfma_f32_16x16x32_bf16(a, wf, a3[m], 0, 0, 0);
            }
        }
    }
    // ---- epilogue: scalar atomic scatter-add straight from registers
    {
        float bs = b3[wv * 16 + lr];
        #pragma unroll
        for (int m = 0; m < 4; m++)
            #pragma unroll
            for (int r = 0; r < 4; r++) {
                int row = m * 16 + qd * 4 + r;
                atomicAdd(out1 + (size_t)dstL[row] * 64 + wv * 16 + lr,
                          a3[m][r] + bs);
            }
    }
}

extern "C" void kernel_launch(void* const* d_in, const int* in_sizes, int n_in,
                              void* d_out, int out_size, void* d_ws, size_t ws_size,
                              hipStream_t stream) {
    const float* nf  = (const float*)d_in[0];
    const float* ef  = (const float*)d_in[1];
    const float* st  = (const float*)d_in[2];
    const float* mW1 = (const float*)d_in[3];
    const float* mb1 = (const float*)d_in[4];
    const float* mW2 = (const float*)d_in[5];
    const float* mb2 = (const float*)d_in[6];
    const float* mW3 = (const float*)d_in[7];
    const float* mb3 = (const float*)d_in[8];
    const float* uW1 = (const float*)d_in[9];
    const float* ub1 = (const float*)d_in[10];
    const float* uW2 = (const float*)d_in[11];
    const float* ub2 = (const float*)d_in[12];
    const int*  eidx = (const int*)d_in[13];

    float* out0 = (float*)d_out;
    float* out1 = out0 + (size_t)NN * 64;
    char*  ws   = (char*)d_ws;
    u16t*  wp   = (u16t*)ws;
    u16t*  nfb  = (u16t*)(ws + NFB_OFF);
    u16t*  stb  = (u16t*)(ws + STB_OFF);

    prep_k<<<PB_PACK + PB_ZERO + PB_NF + PB_ST, 256, 0, stream>>>(
        mW1, mW2, mW3, uW1, uW2, wp, (float4*)out1, nf, nfb, st, stb);
    fused_k<<<NB_EDGE + NB_NODE, 256, 0, stream>>>(
        nfb, stb, nf, ef, mb1, mb2, mb3, ub1, ub2, eidx, wp, out0, out1);
}

// Round 4
// 364.858 us; speedup vs baseline: 1.4010x; 1.4010x over previous
//
#include <hip/hip_runtime.h>
#include <stdint.h>

typedef unsigned short u16t;
typedef unsigned int   u32t;
typedef __attribute__((ext_vector_type(8))) short frag8;   // 8 bf16 = 4 VGPRs
typedef __attribute__((ext_vector_type(4))) float fragc;   // 4 fp32 acc

#define NN 50000
#define NE 800000
#define NB_EDGE 12500          // edge blocks (64 edges each; NE = 64*12500 exactly)
#define NB_NODE 782            // node-MLP blocks (64 nodes each)

// packed-weight offsets in u16 elements within d_ws (weights: 139264 B)
#define W1P 0
#define W2P 24576
#define W3P 40960
#define U1P 49152
#define U2P 61440
// bf16 mirrors of nf/st in d_ws (byte offsets; both 16B-aligned)
#define NFB_OFF 139264                     // u16 nfb[NN*64]  (6.4 MB)
#define STB_OFF (NFB_OFF + 6400000)        // u16 stb[NN*32]  (3.2 MB)

// prep grid partition
#define PB_PACK 34
#define PB_ZERO 3125           // zero out1: NN*16 float4
#define PB_NF   1563           // cvt nf: NN*64 = 3.2M elems, 2048/block
#define PB_ST   782            // cvt st: NN*32 = 1.6M elems

__device__ __forceinline__ u16t f2bf(float f) {
    u32t x = __builtin_bit_cast(u32t, f);
    x = x + 0x7FFFu + ((x >> 16) & 1u);   // RNE
    return (u16t)(x >> 16);
}

__device__ __forceinline__ u32t pack_bf2(float x, float y) {
#if __has_builtin(__builtin_amdgcn_cvt_pk_bf16_f32)
    typedef __attribute__((ext_vector_type(2))) __bf16 bfv2;
    bfv2 r = __builtin_amdgcn_cvt_pk_bf16_f32(x, y);
    return __builtin_bit_cast(u32t, r);
#else
    return (u32t)f2bf(x) | ((u32t)f2bf(y) << 16);
#endif
}

// ---------------------------------------------------------------------------
// Weight prepack core: W (K x N row-major fp32) -> bf16 frag order.
// The packed layout serves as BOTH a B-fragment (col = lane&15) and an
// A-fragment (row = lane&15) thanks to the symmetric MFMA operand layouts.
// ---------------------------------------------------------------------------
__device__ __forceinline__ void prepack_one(int t, const float* w1, const float* w2,
                                            const float* w3, const float* u1,
                                            const float* u2, u16t* out) {
    const float* src; u16t* dst; int id, K, N;
    if (t < 3072)      { id = t;        K = 192; N = 128; src = w1; dst = out + W1P; }
    else if (t < 5120) { id = t - 3072; K = 128; N = 128; src = w2; dst = out + W2P; }
    else if (t < 6144) { id = t - 5120; K = 128; N = 64;  src = w3; dst = out + W3P; }
    else if (t < 7680) { id = t - 6144; K = 96;  N = 128; src = u1; dst = out + U1P; }
    else if (t < 8704) { id = t - 7680; K = 128; N = 64;  src = u2; dst = out + U2P; }
    else return;
    int lane = id & 63;
    int fl   = id >> 6;
    int ksteps = K >> 5;
    int nb = fl / ksteps, ks = fl - nb * ksteps;
    int n  = nb * 16 + (lane & 15);
    int k0 = ks * 32 + (lane >> 4) * 8;
    const float* s = src + (size_t)k0 * N + n;
    uint4 v;
    v.x = pack_bf2(s[0],           s[(size_t)N]);
    v.y = pack_bf2(s[2*(size_t)N], s[3*(size_t)N]);
    v.z = pack_bf2(s[4*(size_t)N], s[5*(size_t)N]);
    v.w = pack_bf2(s[6*(size_t)N], s[7*(size_t)N]);
    *(uint4*)(dst + (size_t)id * 8) = v;
}

// fused prep: prepack weights | zero out1 | cvt nf->bf16 | cvt st->bf16
__global__ void prep_k(const float* __restrict__ w1, const float* __restrict__ w2,
                       const float* __restrict__ w3, const float* __restrict__ u1,
                       const float* __restrict__ u2, u16t* __restrict__ wp,
                       float4* __restrict__ out1v,
                       const float* __restrict__ nf, u16t* __restrict__ nfb,
                       const float* __restrict__ st, u16t* __restrict__ stb) {
    int b = blockIdx.x;
    if (b < PB_PACK) {
        prepack_one(b * 256 + threadIdx.x, w1, w2, w3, u1, u2, wp);
    } else if (b < PB_PACK + PB_ZERO) {
        int i = (b - PB_PACK) * 256 + threadIdx.x;
        if (i < NN * 16) out1v[i] = make_float4(0.f, 0.f, 0.f, 0.f);
    } else if (b < PB_PACK + PB_ZERO + PB_NF) {
        int i = ((b - PB_PACK - PB_ZERO) * 256 + threadIdx.x) * 8;
        if (i < NN * 64) {
            float4 a = *(const float4*)(nf + i);
            float4 c = *(const float4*)(nf + i + 4);
            uint4 v;
            v.x = pack_bf2(a.x, a.y); v.y = pack_bf2(a.z, a.w);
            v.z = pack_bf2(c.x, c.y); v.w = pack_bf2(c.z, c.w);
            *(uint4*)(nfb + i) = v;
        }
    } else {
        int i = ((b - PB_PACK - PB_ZERO - PB_NF) * 256 + threadIdx.x) * 8;
        if (i < NN * 32) {
            float4 a = *(const float4*)(st + i);
            float4 c = *(const float4*)(st + i + 4);
            uint4 v;
            v.x = pack_bf2(a.x, a.y); v.y = pack_bf2(a.z, a.w);
            v.z = pack_bf2(c.x, c.y); v.w = pack_bf2(c.z, c.w);
            *(uint4*)(stb + i) = v;
        }
    }
}

// ---------------------------------------------------------------------------
// Fused main kernel — R0 structure + XOR-swizzled LDS (no pads) + transposed
// L1/L2 outputs (mfma(W,X)) giving packed conflict-free 8B H-writes.
// LDS: X 64x192 bf16 (24576 B, natural stride, chunk c stored at c^(row&7));
//      H/H' 64x128 overlays the same region after X is consumed.
// L3 / final layers keep mfma(X,W) order for coalesced atomics / out0 stores.
// ---------------------------------------------------------------------------
__global__ __launch_bounds__(256, 6)
void fused_k(const u16t* __restrict__ nfb, const u16t* __restrict__ stb,
             const float* __restrict__ nf, const float* __restrict__ ef,
             const float* __restrict__ b1, const float* __restrict__ b2,
             const float* __restrict__ b3, const float* __restrict__ ub1,
             const float* __restrict__ ub2, const int* __restrict__ eidx,
             const u16t* __restrict__ wp,
             float* __restrict__ out0, float* __restrict__ out1) {
    __shared__ __align__(16) u16t R[64 * 192];   // 24576 B
    __shared__ int dstL[64];
    const int tid  = threadIdx.x;
    const int lane = tid & 63;
    const int wv   = tid >> 6;
    const int lr   = lane & 15;
    const int qd   = lane >> 4;
    const int sw   = lr & 7;

    if (blockIdx.x >= NB_EDGE) {
        // ---------------- node role (barrier-free, wave-private H rows) ----
        const int n0  = (blockIdx.x - NB_EDGE) * 64;
        const int m16 = wv * 16;
        int nd  = n0 + m16 + lr;
        int ncl = nd < NN ? nd : NN - 1;          // clamp for loads

        fragc acc[8];
        #pragma unroll
        for (int n = 0; n < 8; n++) acc[n] = (fragc){0.f, 0.f, 0.f, 0.f};
        {
            const frag8* w = (const frag8*)(wp + U1P);
            #pragma unroll
            for (int ks = 0; ks < 3; ks++) {
                frag8 bfr;   // X[node=m16+lr][k] — serves as B-frag (col=lr)
                if (ks < 2) bfr = *(const frag8*)(nfb + (size_t)ncl * 64 + ks * 32 + qd * 8);
                else        bfr = *(const frag8*)(stb + (size_t)ncl * 32 + qd * 8);
                #pragma unroll
                for (int n = 0; n < 8; n++)
                    acc[n] = __builtin_amdgcn_mfma_f32_16x16x32_bf16(
                        w[(n * 3 + ks) * 64 + lane], bfr, acc[n], 0, 0, 0);
            }
        }
        // packed H write: lane holds H[node=m16+lr][n*16+qd*4 .. +4]
        #pragma unroll
        for (int n = 0; n < 8; n++) {
            float4 bq = *(const float4*)(ub1 + n * 16 + qd * 4);
            int cc = n * 2 + (qd >> 1);
            float v0 = acc[n][0] + bq.x; v0 = v0 > 0.f ? v0 : 0.f;
            float v1 = acc[n][1] + bq.y; v1 = v1 > 0.f ? v1 : 0.f;
            float v2 = acc[n][2] + bq.z; v2 = v2 > 0.f ? v2 : 0.f;
            float v3 = acc[n][3] + bq.w; v3 = v3 > 0.f ? v3 : 0.f;
            uint2 hw; hw.x = pack_bf2(v0, v1); hw.y = pack_bf2(v2, v3);
            *(uint2*)(R + (m16 + lr) * 128 + ((cc ^ sw) << 3) + (qd & 1) * 4) = hw;
        }
        // same-wave RAW on LDS: compiler inserts lgkmcnt; no barrier needed
        fragc a2[4];
        #pragma unroll
        for (int n = 0; n < 4; n++) a2[n] = (fragc){0.f, 0.f, 0.f, 0.f};
        {
            const frag8* w = (const frag8*)(wp + U2P);
            #pragma unroll
            for (int ks = 0; ks < 4; ks++) {
                int c = ks * 4 + qd;
                frag8 a = *(const frag8*)(R + (m16 + lr) * 128 + ((c ^ sw) << 3));
                #pragma unroll
                for (int n = 0; n < 4; n++)
                    a2[n] = __builtin_amdgcn_mfma_f32_16x16x32_bf16(
                        a, w[(n * 4 + ks) * 64 + lane], a2[n], 0, 0, 0);
            }
        }
        #pragma unroll
        for (int n = 0; n < 4; n++) {
            float bs = ub2[n * 16 + lr];
            #pragma unroll
            for (int r = 0; r < 4; r++) {
                int nd2 = n0 + m16 + qd * 4 + r;
                if (nd2 < NN) {
                    int col = n * 16 + lr;
                    out0[(size_t)nd2 * 64 + col] = nf[(size_t)nd2 * 64 + col] + a2[n][r] + bs;
                }
            }
        }
        return;
    }

    // ---------------- edge role ----------------
    const int e0  = blockIdx.x * 64;
    const int nb0 = 2 * wv, nb1 = 2 * wv + 1;

    { // stage X (swizzled): chunks 0..15 = nfb[s]|nfb[d], 16..19 = ef, 20..23 = stb[s]
        int el = tid >> 2, p = tid & 3;
        int e = e0 + el;
        int s = eidx[2 * e], d = eidx[2 * e + 1];
        const uint4* nsb = (const uint4*)(nfb + (size_t)s * 64);
        const uint4* ndb = (const uint4*)(nfb + (size_t)d * 64);
        const uint4* spb = (const uint4*)(stb + (size_t)s * 32);
        u16t* xr = R + el * 192;
        const int k = el & 7;
        #pragma unroll
        for (int g = p; g < 20; g += 4) {
            uint4 v; int c;
            if (g < 8)       { v = nsb[g];      c = g; }
            else if (g < 16) { v = ndb[g - 8];  c = g; }
            else             { v = spb[g - 16]; c = g + 4; }
            *(uint4*)(xr + ((c ^ k) << 3)) = v;
        }
        const float4* epf = (const float4*)(ef + (size_t)e * 32);
        #pragma unroll
        for (int h = p; h < 8; h += 4) {
            float4 v = epf[h];
            uint2 pk;
            pk.x = pack_bf2(v.x, v.y);
            pk.y = pack_bf2(v.z, v.w);
            int c = 16 + (h >> 1);
            *(uint2*)(xr + ((c ^ k) << 3) + (h & 1) * 4) = pk;
        }
    }
    if (tid < 64) dstL[tid] = eidx[2 * (e0 + tid) + 1];
    __syncthreads();             // B1: X + dstL visible

    // ---- layer 1: H^T = W1^T(128x192) . X^T ; wave owns nout tiles nb0,nb1
    fragc acc[2][4];
    #pragma unroll
    for (int i = 0; i < 2; i++)
        #pragma unroll
        for (int m = 0; m < 4; m++) acc[i][m] = (fragc){0.f, 0.f, 0.f, 0.f};
    {
        const frag8* w = (const frag8*)(wp + W1P);
        #pragma unroll
        for (int ks = 0; ks < 6; ks++) {
            frag8 w0 = w[(nb0 * 6 + ks) * 64 + lane];
            frag8 w1 = w[(nb1 * 6 + ks) * 64 + lane];
            int c = ks * 4 + qd;
            #pragma unroll
            for (int m = 0; m < 4; m++) {
                frag8 x = *(const frag8*)(R + (m * 16 + lr) * 192 + ((c ^ sw) << 3));
                acc[0][m] = __builtin_amdgcn_mfma_f32_16x16x32_bf16(w0, x, acc[0][m], 0, 0, 0);
                acc[1][m] = __builtin_amdgcn_mfma_f32_16x16x32_bf16(w1, x, acc[1][m], 0, 0, 0);
            }
        }
    }
    __syncthreads();             // B2: all X reads done, R reusable as H
    // packed H write: lane holds H[edge=m*16+lr][nb*16+qd*4 .. +4]
    #pragma unroll
    for (int i = 0; i < 2; i++) {
        int nb = nb0 + i;
        float4 bq = *(const float4*)(b1 + nb * 16 + qd * 4);
        int cc = nb * 2 + (qd >> 1);
        #pragma unroll
        for (int m = 0; m < 4; m++) {
            float v0 = acc[i][m][0] + bq.x; v0 = v0 > 0.f ? v0 : 0.f;
            float v1 = acc[i][m][1] + bq.y; v1 = v1 > 0.f ? v1 : 0.f;
            float v2 = acc[i][m][2] + bq.z; v2 = v2 > 0.f ? v2 : 0.f;
            float v3 = acc[i][m][3] + bq.w; v3 = v3 > 0.f ? v3 : 0.f;
            uint2 hw; hw.x = pack_bf2(v0, v1); hw.y = pack_bf2(v2, v3);
            *(uint2*)(R + (m * 16 + lr) * 128 + ((cc ^ sw) << 3) + (qd & 1) * 4) = hw;
        }
    }
    __syncthreads();             // B3: H complete

    // ---- layer 2: H'(transposed out) = W2^T . H^T
    #pragma unroll
    for (int i = 0; i < 2; i++)
        #pragma unroll
        for (int m = 0; m < 4; m++) acc[i][m] = (fragc){0.f, 0.f, 0.f, 0.f};
    {
        const frag8* w = (const frag8*)(wp + W2P);
        #pragma unroll
        for (int ks = 0; ks < 4; ks++) {
            frag8 w0 = w[(nb0 * 4 + ks) * 64 + lane];
            frag8 w1 = w[(nb1 * 4 + ks) * 64 + lane];
            int c = ks * 4 + qd;
            #pragma unroll
            for (int m = 0; m < 4; m++) {
                frag8 x = *(const frag8*)(R + (m * 16 + lr) * 128 + ((c ^ sw) << 3));
                acc[0][m] = __builtin_amdgcn_mfma_f32_16x16x32_bf16(w0, x, acc[0][m], 0, 0, 0);
                acc[1][m] = __builtin_amdgcn_mfma_f32_16x16x32_bf16(w1, x, acc[1][m], 0, 0, 0);
            }
        }
    }
    __syncthreads();             // B4: all H reads done
    #pragma unroll
    for (int i = 0; i < 2; i++) {
        int nb = nb0 + i;
        float4 bq = *(const float4*)(b2 + nb * 16 + qd * 4);
        int cc = nb * 2 + (qd >> 1);
        #pragma unroll
        for (int m = 0; m < 4; m++) {
            float v0 = acc[i][m][0] + bq.x; v0 = v0 > 0.f ? v0 : 0.f;
            float v1 = acc[i][m][1] + bq.y; v1 = v1 > 0.f ? v1 : 0.f;
            float v2 = acc[i][m][2] + bq.z; v2 = v2 > 0.f ? v2 : 0.f;
            float v3 = acc[i][m][3] + bq.w; v3 = v3 > 0.f ? v3 : 0.f;
            uint2 hw; hw.x = pack_bf2(v0, v1); hw.y = pack_bf2(v2, v3);
            *(uint2*)(R + (m * 16 + lr) * 128 + ((cc ^ sw) << 3) + (qd & 1) * 4) = hw;
        }
    }
    __syncthreads();             // B5: H' complete

    // ---- layer 3 (original order -> coalesced atomics): wave owns 16 cols
    fragc a3[4];
    #pragma unroll
    for (int m = 0; m < 4; m++) a3[m] = (fragc){0.f, 0.f, 0.f, 0.f};
    {
        const frag8* w = (const frag8*)(wp + W3P);
        #pragma unroll
        for (int ks = 0; ks < 4; ks++) {
            frag8 wf = w[(wv * 4 + ks) * 64 + lane];
            int c = ks * 4 + qd;
            #pragma unroll
            for (int m = 0; m < 4; m++) {
                frag8 a = *(const frag8*)(R + (m * 16 + lr) * 128 + ((c ^ sw) << 3));
                a3[m] = __builtin_amdgcn_mfma_f32_16x16x32_bf16(a, wf, a3[m], 0, 0, 0);
            }
        }
    }
    // ---- epilogue: scalar atomic scatter-add straight from registers
    {
        float bs = b3[wv * 16 + lr];
        #pragma unroll
        for (int m = 0; m < 4; m++)
            #pragma unroll
            for (int r = 0; r < 4; r++) {
                int row = m * 16 + qd * 4 + r;
                atomicAdd(out1 + (size_t)dstL[row] * 64 + wv * 16 + lr,
                          a3[m][r] + bs);
            }
    }
}

extern "C" void kernel_launch(void* const* d_in, const int* in_sizes, int n_in,
                              void* d_out, int out_size, void* d_ws, size_t ws_size,
                              hipStream_t stream) {
    const float* nf  = (const float*)d_in[0];
    const float* ef  = (const float*)d_in[1];
    const float* st  = (const float*)d_in[2];
    const float* mW1 = (const float*)d_in[3];
    const float* mb1 = (const float*)d_in[4];
    const float* mW2 = (const float*)d_in[5];
    const float* mb2 = (const float*)d_in[6];
    const float* mW3 = (const float*)d_in[7];
    const float* mb3 = (const float*)d_in[8];
    const float* uW1 = (const float*)d_in[9];
    const float* ub1 = (const float*)d_in[10];
    const float* uW2 = (const float*)d_in[11];
    const float* ub2 = (const float*)d_in[12];
    const int*  eidx = (const int*)d_in[13];

    float* out0 = (float*)d_out;
    float* out1 = out0 + (size_t)NN * 64;
    char*  ws   = (char*)d_ws;
    u16t*  wp   = (u16t*)ws;
    u16t*  nfb  = (u16t*)(ws + NFB_OFF);
    u16t*  stb  = (u16t*)(ws + STB_OFF);

    prep_k<<<PB_PACK + PB_ZERO + PB_NF + PB_ST, 256, 0, stream>>>(
        mW1, mW2, mW3, uW1, uW2, wp, (float4*)out1, nf, nfb, st, stb);
    fused_k<<<NB_EDGE + NB_NODE, 256, 0, stream>>>(
        nfb, stb, nf, ef, mb1, mb2, mb3, ub1, ub2, eidx, wp, out0, out1);
}